// Round 1
// baseline (970.940 us; speedup 1.0000x reference)
//
#include <hip/hip_runtime.h>
#include <math.h>

#define B_ 8
#define Q_ 100
#define T_ 50
#define HW_ 65536
#define QT 20
#define NSEG 8
#define SEG (HW_ / NSEG)   // 8192
#define CHUNK 128
#define C4 (CHUNK / 4)     // 32 float4 per row-chunk

// workspace layout (floats)
#define WS_SNEG 0          // [800)  sum softplus(x) per (b,q)
#define WS_SS   800        // [800)  sum sigmoid(x) per (b,q)
#define WS_ST   1600       // [400)  sum t per (b,t)
#define WS_DOTX 2000       // [40000) dot(x,t)
#define WS_DOTS 42000      // [40000) dot(sigmoid(x),t)
#define WS_TOTAL 82000

__global__ void zero_ws(float* ws, int n) {
    int i = blockIdx.x * blockDim.x + threadIdx.x;
    if (i < n) ws[i] = 0.f;
}

__global__ __launch_bounds__(256) void row_sums(const float* __restrict__ pred,
                                                const int* __restrict__ tgt,
                                                float* __restrict__ ws) {
    int row = blockIdx.x;
    int tid = threadIdx.x;
    float s0 = 0.f, s1 = 0.f;

    if (row < B_ * Q_) {
        const float4* p = (const float4*)(pred + (size_t)row * HW_);
        for (int i = tid; i < HW_ / 4; i += 256) {
            float4 v = p[i];
#pragma unroll
            for (int j = 0; j < 4; j++) {
                float x = (&v.x)[j];
                float e = __expf(-fabsf(x));
                // softplus(x) = max(x,0) + log1p(exp(-|x|))
                s0 += fmaxf(x, 0.f) + log1pf(e);
                // sigmoid(x)
                s1 += (x >= 0.f) ? 1.f / (1.f + e) : e / (1.f + e);
            }
        }
    } else {
        int r = row - B_ * Q_;
        const int4* p = (const int4*)(tgt + (size_t)r * HW_);
        for (int i = tid; i < HW_ / 4; i += 256) {
            int4 v = p[i];
            s0 += (float)(v.x + v.y + v.z + v.w);
        }
    }

    // wave64 reduce
    for (int off = 32; off > 0; off >>= 1) {
        s0 += __shfl_down(s0, off);
        s1 += __shfl_down(s1, off);
    }
    __shared__ float red[8];
    int lane = tid & 63, w = tid >> 6;
    if (lane == 0) { red[w] = s0; red[4 + w] = s1; }
    __syncthreads();
    if (tid == 0) {
        float a = red[0] + red[1] + red[2] + red[3];
        float b = red[4] + red[5] + red[6] + red[7];
        if (row < B_ * Q_) {
            ws[WS_SNEG + row] = a;
            ws[WS_SS + row] = b;
        } else {
            ws[WS_ST + (row - B_ * Q_)] = a;
        }
    }
}

__global__ __launch_bounds__(256) void dots_kernel(const float* __restrict__ pred,
                                                   const int* __restrict__ tgt,
                                                   float* __restrict__ ws) {
    int seg = blockIdx.x;  // 0..NSEG-1
    int qb  = blockIdx.y;  // 0..4
    int b   = blockIdx.z;  // 0..7
    int tid = threadIdx.x;

    __shared__ float xs[QT][132];
    __shared__ float sg[QT][132];
    __shared__ float ts[T_][132];

    float accx[2][2] = {{0.f, 0.f}, {0.f, 0.f}};
    float accs[2][2] = {{0.f, 0.f}, {0.f, 0.f}};
    int qi = tid / 25;   // 0..9 (10 = inactive)
    int ti = tid % 25;   // 0..24
    bool active = tid < 250;

    const size_t xbase = ((size_t)b * Q_ + (size_t)qb * QT) * HW_ + (size_t)seg * SEG;
    const size_t tbase = ((size_t)b * T_) * HW_ + (size_t)seg * SEG;

    for (int ch = 0; ch < SEG / CHUNK; ++ch) {
        int cb = ch * CHUNK;
        __syncthreads();  // protect LDS from previous iteration's readers
        // stage x tile + sigmoid tile
        for (int i = tid; i < QT * C4; i += 256) {
            int r = i >> 5, c = i & 31;
            float4 v = *(const float4*)(pred + xbase + (size_t)r * HW_ + cb + c * 4);
            float4 s;
#pragma unroll
            for (int j = 0; j < 4; j++) {
                float x = (&v.x)[j];
                float e = __expf(-fabsf(x));
                (&s.x)[j] = (x >= 0.f) ? 1.f / (1.f + e) : e / (1.f + e);
            }
            *(float4*)&xs[r][c * 4] = v;
            *(float4*)&sg[r][c * 4] = s;
        }
        // stage t tile (int -> float)
        for (int i = tid; i < T_ * C4; i += 256) {
            int r = i >> 5, c = i & 31;
            int4 v = *(const int4*)(tgt + tbase + (size_t)r * HW_ + cb + c * 4);
            float4 f = make_float4((float)v.x, (float)v.y, (float)v.z, (float)v.w);
            *(float4*)&ts[r][c * 4] = f;
        }
        __syncthreads();

        if (active) {
#pragma unroll 4
            for (int k4 = 0; k4 < C4; k4++) {
                float4 xa0 = *(float4*)&xs[qi][k4 * 4];
                float4 xa1 = *(float4*)&xs[qi + 10][k4 * 4];
                float4 sa0 = *(float4*)&sg[qi][k4 * 4];
                float4 sa1 = *(float4*)&sg[qi + 10][k4 * 4];
                float4 tb0 = *(float4*)&ts[ti][k4 * 4];
                float4 tb1 = *(float4*)&ts[ti + 25][k4 * 4];
#pragma unroll
                for (int j = 0; j < 4; j++) {
                    float x0 = (&xa0.x)[j], x1 = (&xa1.x)[j];
                    float s0 = (&sa0.x)[j], s1 = (&sa1.x)[j];
                    float t0 = (&tb0.x)[j], t1 = (&tb1.x)[j];
                    accx[0][0] = fmaf(x0, t0, accx[0][0]);
                    accx[0][1] = fmaf(x0, t1, accx[0][1]);
                    accx[1][0] = fmaf(x1, t0, accx[1][0]);
                    accx[1][1] = fmaf(x1, t1, accx[1][1]);
                    accs[0][0] = fmaf(s0, t0, accs[0][0]);
                    accs[0][1] = fmaf(s0, t1, accs[0][1]);
                    accs[1][0] = fmaf(s1, t0, accs[1][0]);
                    accs[1][1] = fmaf(s1, t1, accs[1][1]);
                }
            }
        }
    }

    if (active) {
#pragma unroll
        for (int a = 0; a < 2; a++)
#pragma unroll
            for (int c = 0; c < 2; c++) {
                int q = qb * QT + qi + a * 10;
                int t = ti + c * 25;
                size_t idx = ((size_t)b * Q_ + q) * T_ + t;
                atomicAdd(&ws[WS_DOTX + idx], accx[a][c]);
                atomicAdd(&ws[WS_DOTS + idx], accs[a][c]);
            }
    }
}

__global__ void finalize(const float* __restrict__ ws, float* __restrict__ out) {
    int i = blockIdx.x * blockDim.x + threadIdx.x;
    if (i >= B_ * Q_ * T_) return;
    int b = i / (Q_ * T_);
    int r = i % (Q_ * T_);
    int q = r / T_;
    int t = r % T_;
    float sneg = ws[WS_SNEG + b * Q_ + q];
    float ssum = ws[WS_SS + b * Q_ + q];
    float st   = ws[WS_ST + b * T_ + t];
    float dx = ws[WS_DOTX + i];
    float ds = ws[WS_DOTS + i];
    float ce = (sneg - dx) * (1.f / (float)HW_);
    float dice = 1.f - (2.f * ds + 1.f) / (ssum + st + 1.f);
    out[i] = ce + dice;
}

extern "C" void kernel_launch(void* const* d_in, const int* in_sizes, int n_in,
                              void* d_out, int out_size, void* d_ws, size_t ws_size,
                              hipStream_t stream) {
    const float* pred = (const float*)d_in[0];
    const int* tgt = (const int*)d_in[1];
    float* ws = (float*)d_ws;
    float* out = (float*)d_out;

    zero_ws<<<(WS_TOTAL + 255) / 256, 256, 0, stream>>>(ws, WS_TOTAL);
    row_sums<<<B_ * Q_ + B_ * T_, 256, 0, stream>>>(pred, tgt, ws);
    dim3 g2(NSEG, Q_ / QT, B_);
    dots_kernel<<<g2, 256, 0, stream>>>(pred, tgt, ws);
    finalize<<<(B_ * Q_ * T_ + 255) / 256, 256, 0, stream>>>(ws, out);
}

// Round 2
// 420.754 us; speedup vs baseline: 2.3076x; 2.3076x over previous
//
#include <hip/hip_runtime.h>
#include <math.h>

#define B_ 8
#define Q_ 100
#define T_ 50
#define HW_ 65536
#define NSEG 64
#define SEG (HW_ / NSEG)     // 1024 K elems per block
#define KC 64                // K-chunk staged in LDS
#define NCH (SEG / KC)       // 16 chunks
#define MP 101               // stored M (100 q + ones-row products row)
#define NP 64                // stored N (50 t + sigma-sum col)
#define LDP 72               // LDS row stride in bf16 (64 + 8 pad)

// workspace layout (floats)
#define DSZ (B_ * MP * NP)   // 51712
#define WS_D1 0
#define WS_D2 DSZ
#define WS_SNEG (2 * DSZ)    // 800
#define WS_TOTAL (2 * DSZ + B_ * Q_)

typedef __attribute__((ext_vector_type(8))) short bf16x8;
typedef __attribute__((ext_vector_type(4))) float f32x4;

__device__ __forceinline__ unsigned short f2bf(float f) {
    union { float f; unsigned u; } v; v.f = f;
    unsigned r = v.u + 0x7FFF + ((v.u >> 16) & 1);
    return (unsigned short)(r >> 16);
}

__global__ void zero_ws(float* ws) {
    int i = blockIdx.x * blockDim.x + threadIdx.x;
    if (i < WS_TOTAL) ws[i] = 0.f;
}

__global__ __launch_bounds__(256) void gemm_fused(const float* __restrict__ pred,
                                                  const int* __restrict__ tgt,
                                                  float* __restrict__ ws) {
    const int seg = blockIdx.x;      // 0..NSEG-1
    const int b   = blockIdx.y;      // 0..7
    const int tid = threadIdx.x;

    __shared__ short xs[112][LDP];
    __shared__ short ss[112][LDP];
    __shared__ short ts[64][LDP];
    __shared__ float sneg_l[Q_];

    f32x4 accx[7], accs[7];
#pragma unroll
    for (int i = 0; i < 7; i++) { accx[i] = (f32x4)(0.f); accs[i] = (f32x4)(0.f); }
    float snegr[7] = {0.f, 0.f, 0.f, 0.f, 0.f, 0.f, 0.f};

    // one-time pad init: xs rows 100..111 = 0; ss row 100 = 1.0, rows 101..111 = 0
    for (int i = tid; i < 12 * LDP; i += 256) {
        int r = 100 + i / LDP, c = i % LDP;
        xs[r][c] = 0;
        ss[r][c] = (r == 100) ? (short)0x3F80 : (short)0;
    }
    // ts row 50 = 1.0 (sigma/x row-sum column), rows 51..63 = 0
    for (int i = tid; i < 14 * LDP; i += 256) {
        int r = 50 + i / LDP, c = i % LDP;
        ts[r][c] = (r == 50) ? (short)0x3F80 : (short)0;
    }
    if (tid < Q_) sneg_l[tid] = 0.f;

    const int lane = tid & 63;
    const int wave = tid >> 6;
    const int quad = lane >> 4;    // 0..3
    const int l16  = lane & 15;

    const size_t xrow0 = (size_t)b * Q_ * HW_ + (size_t)seg * SEG;
    const size_t trow0 = (size_t)b * T_ * HW_ + (size_t)seg * SEG;

    for (int ch = 0; ch < NCH; ++ch) {
        const int k0 = ch * KC;
        __syncthreads();   // readers of prev chunk done (also covers init on ch=0)

        // ---- stage X: 100 rows x 16 float4 ----
        {
            int j = 0;
            for (int i = tid; i < Q_ * (KC / 4); i += 256, j++) {
                int r = i >> 4, c4 = i & 15;
                float4 v = *(const float4*)(pred + xrow0 + (size_t)r * HW_ + k0 + c4 * 4);
                ushort4 xb, sb;
                float sp = 0.f;
#pragma unroll
                for (int e = 0; e < 4; e++) {
                    float x = (&v.x)[e];
                    float ax = fabsf(x);
                    float ee = __expf(-ax);                 // exp(-|x|)
                    float d = 1.f + ee;
                    float r1 = __builtin_amdgcn_rcpf(d);
                    float sg = (x >= 0.f) ? r1 : ee * r1;   // sigmoid
                    sp += fmaxf(x, 0.f) + 0.69314718056f * __log2f(d);  // softplus
                    (&xb.x)[e] = f2bf(x);
                    (&sb.x)[e] = f2bf(sg);
                }
                snegr[j] += sp;
                *(ushort4*)&xs[r][c4 * 4] = xb;
                *(ushort4*)&ss[r][c4 * 4] = sb;
            }
        }
        // ---- stage T: 50 rows x 16 int4 ----
        for (int i = tid; i < T_ * (KC / 4); i += 256) {
            int r = i >> 4, c4 = i & 15;
            int4 v = *(const int4*)(tgt + trow0 + (size_t)r * HW_ + k0 + c4 * 4);
            ushort4 tb;
            tb.x = v.x ? 0x3F80 : 0;
            tb.y = v.y ? 0x3F80 : 0;
            tb.z = v.z ? 0x3F80 : 0;
            tb.w = v.w ? 0x3F80 : 0;
            *(ushort4*)&ts[r][c4 * 4] = tb;
        }
        __syncthreads();

        // ---- MFMA: wave w owns N-tile w (cols 16w..16w+15), all 7 M-tiles ----
#pragma unroll
        for (int kk = 0; kk < KC / 32; kk++) {
            const int kb = kk * 32 + quad * 8;
            bf16x8 bfrag = *(bf16x8*)&ts[wave * 16 + l16][kb];
#pragma unroll
            for (int mt = 0; mt < 7; mt++) {
                bf16x8 ax = *(bf16x8*)&xs[mt * 16 + l16][kb];
                bf16x8 as = *(bf16x8*)&ss[mt * 16 + l16][kb];
                accx[mt] = __builtin_amdgcn_mfma_f32_16x16x32_bf16(ax, bfrag, accx[mt], 0, 0, 0);
                accs[mt] = __builtin_amdgcn_mfma_f32_16x16x32_bf16(as, bfrag, accs[mt], 0, 0, 0);
            }
        }
    }

    // ---- epilogue: softplus row sums ----
    {
        int j = 0;
        for (int i = tid; i < Q_ * (KC / 4); i += 256, j++) {
            int r = i >> 4;
            atomicAdd(&sneg_l[r], snegr[j]);
        }
    }
    __syncthreads();
    if (tid < Q_) atomicAdd(&ws[WS_SNEG + b * Q_ + tid], sneg_l[tid]);

    // ---- epilogue: D atomics (C/D layout: n=l16, m_within=quad*4+reg) ----
    const int n = wave * 16 + l16;
#pragma unroll
    for (int mt = 0; mt < 7; mt++) {
#pragma unroll
        for (int r = 0; r < 4; r++) {
            int m = mt * 16 + quad * 4 + r;
            if (m < Q_ && n < T_)
                atomicAdd(&ws[WS_D1 + ((size_t)b * MP + m) * NP + n], accx[mt][r]);
            if (m <= Q_ && n <= T_)
                atomicAdd(&ws[WS_D2 + ((size_t)b * MP + m) * NP + n], accs[mt][r]);
        }
    }
}

__global__ void finalize(const float* __restrict__ ws, float* __restrict__ out) {
    int i = blockIdx.x * blockDim.x + threadIdx.x;
    if (i >= B_ * Q_ * T_) return;
    int b = i / (Q_ * T_);
    int r = i % (Q_ * T_);
    int q = r / T_;
    int t = r % T_;
    float dx   = ws[WS_D1 + ((size_t)b * MP + q) * NP + t];
    float ds   = ws[WS_D2 + ((size_t)b * MP + q) * NP + t];
    float ssum = ws[WS_D2 + ((size_t)b * MP + q) * NP + T_];   // Sigma sigmoid
    float st   = ws[WS_D2 + ((size_t)b * MP + Q_) * NP + t];   // Sigma t
    float sneg = ws[WS_SNEG + b * Q_ + q];
    float ce = (sneg - dx) * (1.f / (float)HW_);
    float dice = 1.f - (2.f * ds + 1.f) / (ssum + st + 1.f);
    out[i] = ce + dice;
}

extern "C" void kernel_launch(void* const* d_in, const int* in_sizes, int n_in,
                              void* d_out, int out_size, void* d_ws, size_t ws_size,
                              hipStream_t stream) {
    const float* pred = (const float*)d_in[0];
    const int* tgt = (const int*)d_in[1];
    float* ws = (float*)d_ws;
    float* out = (float*)d_out;

    zero_ws<<<(WS_TOTAL + 255) / 256, 256, 0, stream>>>(ws);
    dim3 g(NSEG, B_, 1);
    gemm_fused<<<g, 256, 0, stream>>>(pred, tgt, ws);
    finalize<<<(B_ * Q_ * T_ + 255) / 256, 256, 0, stream>>>(ws, out);
}

// Round 3
// 398.055 us; speedup vs baseline: 2.4392x; 1.0570x over previous
//
#include <hip/hip_runtime.h>
#include <math.h>

#define B_ 8
#define Q_ 100
#define T_ 50
#define HW_ 65536
#define NSEG 64
#define SEG (HW_ / NSEG)    // 1024 K per block
#define NK32 (SEG / 32)     // 32 K-steps of 32
#define NSTR 52             // N stride in ws (50 t + ssum col + pad)

// workspace layout (floats)
#define DSZ (B_ * Q_ * NSTR)       // 41600
#define WS_D1 0
#define WS_D2 DSZ
#define WS_SNEG (2 * DSZ)          // 800
#define WS_ST (2 * DSZ + B_ * Q_)  // 400
#define WS_TOTAL (2 * DSZ + B_ * Q_ + B_ * T_)

typedef __attribute__((ext_vector_type(8))) short bf16x8;
typedef __attribute__((ext_vector_type(4))) float f32x4;

__device__ __forceinline__ unsigned short f2bf(float f) {
    union { float f; unsigned u; } v; v.f = f;
    unsigned r = v.u + 0x7FFF + ((v.u >> 16) & 1);
    return (unsigned short)(r >> 16);
}

__global__ void zero_ws(float* ws) {
    int i = blockIdx.x * blockDim.x + threadIdx.x;
    if (i < WS_TOTAL) ws[i] = 0.f;
}

// LDS-free, barrier-free fused GEMM. Each wave: M-tiles {wave, wave+4} x all
// 4 N-tiles, fragments loaded straight from global in MFMA layout.
__global__ __launch_bounds__(256, 2) void gemm_fused(const float* __restrict__ pred,
                                                     const int* __restrict__ tgt,
                                                     float* __restrict__ ws) {
    const int seg = blockIdx.x;
    const int b   = blockIdx.y;
    const int tid = threadIdx.x;
    const int wave = tid >> 6;
    const int lane = tid & 63;
    const int quad = lane >> 4;
    const int l16  = lane & 15;

    // A (x) pointers: rows clamped into [0, Q_) — garbage tiles never written
    const float* xptr[2];
#pragma unroll
    for (int mt = 0; mt < 2; ++mt) {
        int m = (wave + mt * 4) * 16 + l16;
        int mr = m < Q_ ? m : Q_ - 1;
        xptr[mt] = pred + ((size_t)b * Q_ + mr) * HW_ + (size_t)seg * SEG + quad * 8;
    }
    // B (t) pointers: rows clamped into [0, T_)
    const int* tptr[4];
    int ones[4];
#pragma unroll
    for (int nt = 0; nt < 4; ++nt) {
        int n = nt * 16 + l16;
        ones[nt] = (n == T_);          // the Sigma-sigmoid ones column
        int nr = n < T_ ? n : T_ - 1;
        tptr[nt] = tgt + ((size_t)b * T_ + nr) * HW_ + (size_t)seg * SEG + quad * 8;
    }

    f32x4 accx[2][4], accs[2][4];
#pragma unroll
    for (int mt = 0; mt < 2; ++mt)
#pragma unroll
        for (int nt = 0; nt < 4; ++nt) {
            accx[mt][nt] = (f32x4)(0.f);
            accs[mt][nt] = (f32x4)(0.f);
        }
    float sneg[2] = {0.f, 0.f};
    float stq[4] = {0.f, 0.f, 0.f, 0.f};

    float4 xrb[2][2][2];
    int4   trb[2][4][2];

    auto loadraw = [&](int ch, float4 xr[2][2], int4 tr[4][2]) {
        const int k = ch * 32;
#pragma unroll
        for (int mt = 0; mt < 2; ++mt) {
            xr[mt][0] = *(const float4*)(xptr[mt] + k);
            xr[mt][1] = *(const float4*)(xptr[mt] + k + 4);
        }
#pragma unroll
        for (int nt = 0; nt < 4; ++nt) {
            tr[nt][0] = *(const int4*)(tptr[nt] + k);
            tr[nt][1] = *(const int4*)(tptr[nt] + k + 4);
        }
    };

    auto compute = [&](float4 xr[2][2], int4 tr[4][2]) {
        bf16x8 tf[4];
#pragma unroll
        for (int nt = 0; nt < 4; ++nt) {
            float cnt = 0.f;
#pragma unroll
            for (int h = 0; h < 2; ++h)
#pragma unroll
                for (int e = 0; e < 4; ++e) {
                    int v = (&tr[nt][h].x)[e];
                    tf[nt][h * 4 + e] = (v || ones[nt]) ? (short)0x3F80 : (short)0;
                    cnt += v ? 1.f : 0.f;
                }
            stq[nt] += cnt;
        }
#pragma unroll
        for (int mt = 0; mt < 2; ++mt) {
            bf16x8 xf, sf;
            float sp = 0.f;
#pragma unroll
            for (int h = 0; h < 2; ++h)
#pragma unroll
                for (int e = 0; e < 4; ++e) {
                    float x = (&xr[mt][h].x)[e];
                    float ax = fabsf(x);
                    float ee = __expf(-ax);
                    float d = 1.f + ee;
                    float r1 = __builtin_amdgcn_rcpf(d);
                    float sg = (x >= 0.f) ? r1 : ee * r1;              // sigmoid
                    sp += fmaxf(x, 0.f) + 0.69314718056f * __log2f(d); // softplus
                    xf[h * 4 + e] = (short)f2bf(x);
                    sf[h * 4 + e] = (short)f2bf(sg);
                }
            sneg[mt] += sp;
#pragma unroll
            for (int nt = 0; nt < 4; ++nt) {
                accx[mt][nt] = __builtin_amdgcn_mfma_f32_16x16x32_bf16(xf, tf[nt], accx[mt][nt], 0, 0, 0);
                accs[mt][nt] = __builtin_amdgcn_mfma_f32_16x16x32_bf16(sf, tf[nt], accs[mt][nt], 0, 0, 0);
            }
        }
    };

    loadraw(0, xrb[0], trb[0]);
#pragma unroll 2
    for (int ch = 0; ch < NK32; ++ch) {
        const int cb = ch & 1;
        if (ch + 1 < NK32) loadraw(ch + 1, xrb[cb ^ 1], trb[cb ^ 1]);
        compute(xrb[cb], trb[cb]);
    }

    // ---- epilogue ----
    // softplus row sums: reduce across the 4 quads (same l16)
#pragma unroll
    for (int mt = 0; mt < 2; ++mt) {
        float v = sneg[mt];
        v += __shfl_xor(v, 16);
        v += __shfl_xor(v, 32);
        int m = (wave + mt * 4) * 16 + l16;
        if (quad == 0 && m < Q_) atomicAdd(&ws[WS_SNEG + b * Q_ + m], v);
    }
    // t row sums (only wave 0's copy — it loaded the full t chunk)
    if (wave == 0) {
#pragma unroll
        for (int nt = 0; nt < 4; ++nt) {
            float v = stq[nt];
            v += __shfl_xor(v, 16);
            v += __shfl_xor(v, 32);
            int n = nt * 16 + l16;
            if (quad == 0 && n < T_) atomicAdd(&ws[WS_ST + b * T_ + n], v);
        }
    }
    // D atomics; C/D layout: col = l16 (n), row-within-tile = quad*4 + r
#pragma unroll
    for (int mt = 0; mt < 2; ++mt) {
        int mtile = (wave + mt * 4) * 16;
#pragma unroll
        for (int nt = 0; nt < 4; ++nt) {
            int n = nt * 16 + l16;
#pragma unroll
            for (int r = 0; r < 4; ++r) {
                int m = mtile + quad * 4 + r;
                if (m < Q_) {
                    size_t idx = ((size_t)b * Q_ + m) * NSTR + n;
                    if (n < T_) atomicAdd(&ws[WS_D1 + idx], accx[mt][nt][r]);
                    if (n <= T_) atomicAdd(&ws[WS_D2 + idx], accs[mt][nt][r]);
                }
            }
        }
    }
}

__global__ void finalize(const float* __restrict__ ws, float* __restrict__ out) {
    int i = blockIdx.x * blockDim.x + threadIdx.x;
    if (i >= B_ * Q_ * T_) return;
    int b = i / (Q_ * T_);
    int r = i % (Q_ * T_);
    int q = r / T_;
    int t = r % T_;
    float dx   = ws[WS_D1 + ((size_t)b * Q_ + q) * NSTR + t];
    float ds   = ws[WS_D2 + ((size_t)b * Q_ + q) * NSTR + t];
    float ssum = ws[WS_D2 + ((size_t)b * Q_ + q) * NSTR + T_];
    float st   = ws[WS_ST + b * T_ + t];
    float sneg = ws[WS_SNEG + b * Q_ + q];
    float ce = (sneg - dx) * (1.f / (float)HW_);
    float dice = 1.f - (2.f * ds + 1.f) / (ssum + st + 1.f);
    out[i] = ce + dice;
}

extern "C" void kernel_launch(void* const* d_in, const int* in_sizes, int n_in,
                              void* d_out, int out_size, void* d_ws, size_t ws_size,
                              hipStream_t stream) {
    const float* pred = (const float*)d_in[0];
    const int* tgt = (const int*)d_in[1];
    float* ws = (float*)d_ws;
    float* out = (float*)d_out;

    zero_ws<<<(WS_TOTAL + 255) / 256, 256, 0, stream>>>(ws);
    dim3 g(NSEG, B_, 1);
    gemm_fused<<<g, 256, 0, stream>>>(pred, tgt, ws);
    finalize<<<(B_ * Q_ * T_ + 255) / 256, 256, 0, stream>>>(ws, out);
}